// Round 7
// baseline (1143.235 us; speedup 1.0000x reference)
//
#include <hip/hip_runtime.h>
#include <math.h>

#define NN 10000
#define NE 20000
#define FIN 128
#define NHEAD 8
#define C1 512
#define C2 256
#define NB 64
#define NOUT 10

typedef _Float16 half8v __attribute__((ext_vector_type(8)));
typedef _Float16 half4v __attribute__((ext_vector_type(4)));
typedef _Float16 half2v __attribute__((ext_vector_type(2)));
typedef float f32x4 __attribute__((ext_vector_type(4)));

template<int VEC> struct VecT;
template<> struct VecT<2> { using T = half2v; };
template<> struct VecT<4> { using T = half4v; };
template<> struct VecT<8> { using T = half8v; };

// monotone float<->uint encoding for atomic max on floats
__device__ __forceinline__ unsigned enc_f(float f) {
    unsigned u = __float_as_uint(f);
    return (u & 0x80000000u) ? ~u : (u | 0x80000000u);
}
__device__ __forceinline__ float dec_f(unsigned e) {
    return (e & 0x80000000u) ? __uint_as_float(e & 0x7fffffffu) : __uint_as_float(~e);
}

// ---------------- conversion / transpose ----------------
__global__ void cvt_f16(const float* __restrict__ in, _Float16* __restrict__ out, int n) {
    int i = blockIdx.x * blockDim.x + threadIdx.x;
    if (i < n) out[i] = (_Float16)in[i];
}

// W [K,N] fp32 -> Wt [N,K] f16 (rows = output cols). block (32,8)
__global__ void transpose_cvt(const float* __restrict__ W, _Float16* __restrict__ Wt,
                              int K, int N) {
    __shared__ float tile[32][33];
    int n0 = blockIdx.x * 32, k0 = blockIdx.y * 32;
    int tx = threadIdx.x, ty = threadIdx.y;
    for (int j = ty; j < 32; j += 8) tile[j][tx] = W[(size_t)(k0 + j) * N + n0 + tx];
    __syncthreads();
    for (int j = ty; j < 32; j += 8)
        Wt[(size_t)(n0 + j) * K + k0 + tx] = (_Float16)tile[tx][j];
}

// Head-stacked V-weight transpose:
// Wv [Cin, NHEAD*Cout] fp32 -> Bt [Cout, NHEAD*Cin] f16 with Bt[c, h*Cin+k] = Wv[k, h*Cout+c]
__global__ void transpose_stack(const float* __restrict__ Wv, _Float16* __restrict__ Bt,
                                int Cin, int Cout) {
    __shared__ float tile[32][33];
    int h = blockIdx.z;
    int c0 = blockIdx.x * 32, k0 = blockIdx.y * 32;
    int tx = threadIdx.x, ty = threadIdx.y;
    for (int j = ty; j < 32; j += 8)
        tile[j][tx] = Wv[(size_t)(k0 + j) * (NHEAD * Cout) + (size_t)h * Cout + c0 + tx];
    __syncthreads();
    for (int j = ty; j < 32; j += 8)
        Bt[(size_t)(c0 + j) * (NHEAD * Cin) + (size_t)h * Cin + k0 + tx] = (_Float16)tile[tx][j];
}

// bvm[c] = (1/H) sum_h bv[h*C + c]
__global__ void bvmean_k(const float* __restrict__ bv, float* __restrict__ bvm, int C) {
    int c = blockIdx.x * blockDim.x + threadIdx.x;
    if (c >= C) return;
    float s = 0.f;
    #pragma unroll
    for (int h = 0; h < NHEAD; ++h) s += bv[h * C + c];
    bvm[c] = s * (1.0f / NHEAD);
}

// ---------------- MFMA GEMM:  C = A[M,K] @ Bt[N,K]^T (+bias | +=C) ----------------
template<bool OUT_HALF, bool ACCUM>
__global__ __launch_bounds__(256) void gemm_tn(
    const _Float16* __restrict__ A, int lda,
    const _Float16* __restrict__ Bt, int ldb,
    const float* __restrict__ bias, void* __restrict__ Cout, int ldc,
    int M, int K)
{
    __shared__ _Float16 As[128][40];   // 80B row stride (16B-aligned)
    __shared__ _Float16 Bs[128][40];
    const int t = threadIdx.x;
    const int m0 = blockIdx.y * 128, n0 = blockIdx.x * 128;
    const int w = t >> 6, lane = t & 63;
    const int wr = w >> 1, wc = w & 1;

    f32x4 acc[4][4];
    #pragma unroll
    for (int m = 0; m < 4; ++m)
        #pragma unroll
        for (int n = 0; n < 4; ++n)
            #pragma unroll
            for (int j = 0; j < 4; ++j) acc[m][n][j] = 0.f;

    for (int k0 = 0; k0 < K; k0 += 32) {
        #pragma unroll
        for (int i = 0; i < 2; ++i) {
            int c = t + i * 256;
            int row = c >> 2, kc = c & 3;
            int gr = m0 + row; gr = gr < M ? gr : M - 1;
            float4 va = *(const float4*)(A + (size_t)gr * lda + k0 + kc * 8);
            *(float4*)(&As[row][kc * 8]) = va;
            float4 vb = *(const float4*)(Bt + (size_t)(n0 + row) * ldb + k0 + kc * 8);
            *(float4*)(&Bs[row][kc * 8]) = vb;
        }
        __syncthreads();
        half8v af[4], bf[4];
        #pragma unroll
        for (int m = 0; m < 4; ++m)
            af[m] = *(const half8v*)(&As[wr * 64 + m * 16 + (lane & 15)][(lane >> 4) * 8]);
        #pragma unroll
        for (int n = 0; n < 4; ++n)
            bf[n] = *(const half8v*)(&Bs[wc * 64 + n * 16 + (lane & 15)][(lane >> 4) * 8]);
        #pragma unroll
        for (int m = 0; m < 4; ++m)
            #pragma unroll
            for (int n = 0; n < 4; ++n)
                acc[m][n] = __builtin_amdgcn_mfma_f32_16x16x32_f16(af[m], bf[n], acc[m][n], 0, 0, 0);
        __syncthreads();
    }
    #pragma unroll
    for (int m = 0; m < 4; ++m) {
        int r0 = m0 + wr * 64 + m * 16 + (lane >> 4) * 4;
        #pragma unroll
        for (int n = 0; n < 4; ++n) {
            int col = n0 + wc * 64 + n * 16 + (lane & 15);
            float b = ACCUM ? 0.f : bias[col];
            #pragma unroll
            for (int r = 0; r < 4; ++r) {
                int row = r0 + r;
                if (row < M) {
                    float v = acc[m][n][r] + b;
                    if (ACCUM) v += ((float*)Cout)[(size_t)row * ldc + col];
                    if (OUT_HALF) ((_Float16*)Cout)[(size_t)row * ldc + col] = (_Float16)v;
                    else          ((float*)Cout)[(size_t)row * ldc + col] = v;
                }
            }
        }
    }
}

// ---------------- CSR build (by dst) ----------------
__global__ void zero_i32(int* __restrict__ p, int n) {
    int i = blockIdx.x * blockDim.x + threadIdx.x;
    if (i < n) p[i] = 0;
}
__global__ void hist_dst(const int* __restrict__ dst, int* __restrict__ deg) {
    int e = blockIdx.x * blockDim.x + threadIdx.x;
    if (e < NE) atomicAdd(&deg[dst[e]], 1);
}
__global__ void scan_deg(const int* __restrict__ deg, int* __restrict__ rowptr,
                         int* __restrict__ cursor, int n) {
    __shared__ int s[256];
    __shared__ int carry;
    int t = threadIdx.x;
    if (t == 0) carry = 0;
    __syncthreads();
    for (int base = 0; base < n; base += 256) {
        int v = (base + t < n) ? deg[base + t] : 0;
        s[t] = v;
        __syncthreads();
        for (int off = 1; off < 256; off <<= 1) {
            int x = (t >= off) ? s[t - off] : 0;
            __syncthreads();
            s[t] += x;
            __syncthreads();
        }
        int excl = carry + s[t] - v;
        if (base + t < n) { rowptr[base + t] = excl; cursor[base + t] = excl; }
        __syncthreads();
        if (t == 255) carry += s[255];
        __syncthreads();
    }
    if (t == 0) rowptr[n] = carry;
}
__global__ void scatter_edges(const int* __restrict__ dst, int* __restrict__ cursor,
                              int* __restrict__ eids) {
    int e = blockIdx.x * blockDim.x + threadIdx.x;
    if (e < NE) {
        int pos = atomicAdd(&cursor[dst[e]], 1);
        eids[pos] = e;
    }
}

// ---------------- segment softmax pieces ----------------
__global__ void init_seg(unsigned* __restrict__ amax, float* __restrict__ denom, int n) {
    int i = blockIdx.x * blockDim.x + threadIdx.x;
    if (i < n) { amax[i] = 0x007FFFFFu; denom[i] = 0.f; }  // enc(-inf)
}

// one wave per edge: alpha[e,h]=dot(Q[dst],K[src])*scale (single head per call)
template<int C>
__global__ void edge_alpha_f(const _Float16* __restrict__ Q, const _Float16* __restrict__ Kh,
                             const int* __restrict__ src, const int* __restrict__ dst,
                             float* __restrict__ alpha, unsigned* __restrict__ amaxU,
                             float scale, int h)
{
    constexpr int VEC = C / 64;
    using vecH = typename VecT<VEC>::T;
    int gi = blockIdx.x * blockDim.x + threadIdx.x;
    int e = gi >> 6, lane = threadIdx.x & 63;
    if (e >= NE) return;
    int s = src[e], d = dst[e];
    vecH q = *(const vecH*)(Q  + (size_t)d * C + lane * VEC);
    vecH k = *(const vecH*)(Kh + (size_t)s * C + lane * VEC);
    float sum = 0.f;
    #pragma unroll
    for (int j = 0; j < VEC; ++j) sum += (float)q[j] * (float)k[j];
    #pragma unroll
    for (int off = 32; off; off >>= 1) sum += __shfl_xor(sum, off);
    if (lane == 0) {
        float al = sum * scale;
        alpha[(size_t)e * NHEAD + h] = al;
        atomicMax(&amaxU[(size_t)d * NHEAD + h], enc_f(al));
    }
}

__global__ void edge_expsum(const float* __restrict__ alpha, const int* __restrict__ dst,
                            const unsigned* __restrict__ amaxU,
                            float* __restrict__ ev, float* __restrict__ denom)
{
    int i = blockIdx.x * blockDim.x + threadIdx.x;
    if (i >= NE * NHEAD) return;
    int e = i >> 3, h = i & 7;
    int d = dst[e];
    float ex = expf(alpha[i] - dec_f(amaxU[(size_t)d * NHEAD + h]));
    ev[i] = ex;
    atomicAdd(&denom[(size_t)d * NHEAD + h], ex);
}

// ---------------- z-aggregation (linearity trick) ----------------
// one wave per node: Z[n, h*C + c] = sum_{e in in(n)} (a[e,h]/H) * X[src(e), c]
// X row width C (the conv INPUT width), G heads per pass, written as f16.
template<int C, int G>
__global__ void zaccum(const _Float16* __restrict__ X, const float* __restrict__ ev,
                       const float* __restrict__ denom, const int* __restrict__ rowptr,
                       const int* __restrict__ eids, const int* __restrict__ src,
                       _Float16* __restrict__ Z, int hbase)
{
    constexpr int VEC = C / 64;
    using vecH = typename VecT<VEC>::T;
    int gi = blockIdx.x * blockDim.x + threadIdx.x;
    int n = gi >> 6, lane = threadIdx.x & 63;
    if (n >= NN) return;
    int beg = rowptr[n], end = rowptr[n + 1];
    float rd[G];
    #pragma unroll
    for (int h = 0; h < G; ++h)
        rd[h] = (1.0f / NHEAD) / (denom[(size_t)n * NHEAD + hbase + h] + 1e-16f);
    float acc[G][VEC];
    #pragma unroll
    for (int h = 0; h < G; ++h)
        #pragma unroll
        for (int j = 0; j < VEC; ++j) acc[h][j] = 0.f;
    for (int i = beg; i < end; ++i) {
        int e = eids[i];
        int s = src[e];
        vecH xv = *(const vecH*)(X + (size_t)s * C + lane * VEC);
        #pragma unroll
        for (int h = 0; h < G; ++h) {
            float cf = ev[(size_t)e * NHEAD + hbase + h] * rd[h];
            #pragma unroll
            for (int j = 0; j < VEC; ++j) acc[h][j] += cf * (float)xv[j];
        }
    }
    #pragma unroll
    for (int h = 0; h < G; ++h) {
        vecH o;
        #pragma unroll
        for (int j = 0; j < VEC; ++j) o[j] = (_Float16)acc[h][j];
        *(vecH*)(Z + (size_t)n * (G * C) + (size_t)h * C + lane * VEC) = o;
    }
}

// ELU(+gated bv-mean) passes
__global__ void elu_cvt_bias(const float* __restrict__ in, _Float16* __restrict__ out,
                             const float* __restrict__ bvm, const int* __restrict__ deg,
                             int total, int cmask, int cshift) {
    int i = blockIdx.x * blockDim.x + threadIdx.x;
    if (i >= total) return;
    int c = i & cmask, n = i >> cshift;
    float v = in[i] + (deg[n] > 0 ? bvm[c] : 0.f);
    v = v > 0.f ? v : expm1f(v);
    out[i] = (_Float16)v;
}
__global__ void elu_bias(float* __restrict__ x, const float* __restrict__ bvm,
                         const int* __restrict__ deg, int total, int cmask, int cshift) {
    int i = blockIdx.x * blockDim.x + threadIdx.x;
    if (i >= total) return;
    int c = i & cmask, n = i >> cshift;
    float v = x[i] + (deg[n] > 0 ? bvm[c] : 0.f);
    x[i] = v > 0.f ? v : expm1f(v);
}

// ---------------- fused global-attention pooling + final fc ----------------
__global__ __launch_bounds__(256) void pool_fused(
    const float* __restrict__ H2, const float* __restrict__ Wg,
    const float* __restrict__ bg, const int* __restrict__ batch,
    const float* __restrict__ Wf, const float* __restrict__ bf,
    float* __restrict__ glogit /*NN scratch*/, float* __restrict__ out)
{
    const int b = blockIdx.x;
    const int t = threadIdx.x, lane = t & 63, w = t >> 6;
    __shared__ int sbeg, send;
    __shared__ float sred[4];
    if (t == 0) {
        int lo = 0, hi = NN;
        while (lo < hi) { int mid = (lo + hi) >> 1; if (batch[mid] < b) lo = mid + 1; else hi = mid; }
        sbeg = lo;
        hi = NN;
        while (lo < hi) { int mid = (lo + hi) >> 1; if (batch[mid] < b + 1) lo = mid + 1; else hi = mid; }
        send = lo;
    }
    __syncthreads();
    const int beg = sbeg, end = send;
    const float bg0 = bg[0];

    float lmax = -INFINITY;
    for (int n = beg + w; n < end; n += 4) {
        float4 h = ((const float4*)(H2 + (size_t)n * C2))[lane];
        float4 wv = ((const float4*)Wg)[lane];
        float sum = h.x * wv.x + h.y * wv.y + h.z * wv.z + h.w * wv.w;
        #pragma unroll
        for (int off = 32; off; off >>= 1) sum += __shfl_xor(sum, off);
        sum += bg0;
        if (lane == 0) glogit[n] = sum;
        lmax = fmaxf(lmax, sum);
    }
    if (lane == 0) sred[w] = lmax;
    __syncthreads();
    float m = fmaxf(fmaxf(sred[0], sred[1]), fmaxf(sred[2], sred[3]));
    if (!isfinite(m)) m = 0.f;
    __syncthreads();

    float ls = 0.f;
    for (int n = beg + t; n < end; n += 256) {
        float e = expf(glogit[n] - m);
        glogit[n] = e;
        ls += e;
    }
    #pragma unroll
    for (int off = 32; off; off >>= 1) ls += __shfl_xor(ls, off);
    if (lane == 0) sred[w] = ls;
    __syncthreads();
    const float denom = sred[0] + sred[1] + sred[2] + sred[3] + 1e-16f;
    __syncthreads();

    float acc = 0.f;
    for (int n = beg; n < end; ++n)
        acc += glogit[n] * H2[(size_t)n * C2 + t];
    const float gc = acc / denom;

    for (int o = 0; o < NOUT; ++o) {
        float p = gc * Wf[t * NOUT + o];
        #pragma unroll
        for (int off = 32; off; off >>= 1) p += __shfl_xor(p, off);
        __syncthreads();
        if (lane == 0) sred[w] = p;
        __syncthreads();
        if (t == 0) out[b * NOUT + o] = sred[0] + sred[1] + sred[2] + sred[3] + bf[o];
    }
}

extern "C" void kernel_launch(void* const* d_in, const int* in_sizes, int n_in,
                              void* d_out, int out_size, void* d_ws, size_t ws_size,
                              hipStream_t stream) {
    (void)in_sizes; (void)n_in; (void)out_size;
    const float* x     = (const float*)d_in[0];
    const int*   ei    = (const int*)  d_in[1];
    const int*   batch = (const int*)  d_in[2];
    const float* Wq1 = (const float*)d_in[3];  const float* bq1 = (const float*)d_in[4];
    const float* Wk1 = (const float*)d_in[5];  const float* bk1 = (const float*)d_in[6];
    const float* Wv1 = (const float*)d_in[7];  const float* bv1 = (const float*)d_in[8];
    const float* Ws1 = (const float*)d_in[9];  const float* bs1 = (const float*)d_in[10];
    const float* Wq2 = (const float*)d_in[11]; const float* bq2 = (const float*)d_in[12];
    const float* Wk2 = (const float*)d_in[13]; const float* bk2 = (const float*)d_in[14];
    const float* Wv2 = (const float*)d_in[15]; const float* bv2 = (const float*)d_in[16];
    const float* Ws2 = (const float*)d_in[17]; const float* bs2 = (const float*)d_in[18];
    const float* Wg  = (const float*)d_in[19]; const float* bg  = (const float*)d_in[20];
    const float* Wf  = (const float*)d_in[21]; const float* bf  = (const float*)d_in[22];

    const int* src = ei;
    const int* dst = ei + NE;

    // ---- workspace layout ----
    char* base = (char*)d_ws;
    size_t off = 0;
    auto alloc = [&](size_t bytes) -> char* {
        char* p = base + off;
        off = (off + bytes + 255) & ~(size_t)255;
        return p;
    };
    _Float16* xb   = (_Float16*)alloc((size_t)NN * FIN * 2);
    _Float16* wtq1 = (_Float16*)alloc((size_t)NHEAD * C1 * FIN * 2);
    _Float16* wtk1 = (_Float16*)alloc((size_t)NHEAD * C1 * FIN * 2);
    _Float16* bvs1 = (_Float16*)alloc((size_t)C1 * NHEAD * FIN * 2);   // [512, 1024]
    _Float16* wts1 = (_Float16*)alloc((size_t)C1 * FIN * 2);
    _Float16* wtq2 = (_Float16*)alloc((size_t)NHEAD * C2 * C1 * 2);
    _Float16* wtk2 = (_Float16*)alloc((size_t)NHEAD * C2 * C1 * 2);
    _Float16* bvs2 = (_Float16*)alloc((size_t)C2 * NHEAD * C1 * 2);    // [256, 4096]
    _Float16* wts2 = (_Float16*)alloc((size_t)C2 * C1 * 2);
    float* acc1 = (float*)alloc((size_t)NN * C1 * 4);
    _Float16* h1b = (_Float16*)alloc((size_t)NN * C1 * 2);
    float* alpha = (float*)alloc((size_t)NE * NHEAD * 4);
    float* ev    = (float*)alloc((size_t)NE * NHEAD * 4);
    unsigned* amaxU = (unsigned*)alloc((size_t)NN * NHEAD * 4);
    float* denom = (float*)alloc((size_t)NN * NHEAD * 4);
    int* deg    = (int*)alloc((size_t)NN * 4);
    int* rowptr = (int*)alloc((size_t)(NN + 1) * 4);
    int* cursor = (int*)alloc((size_t)NN * 4);
    int* eids   = (int*)alloc((size_t)NE * 4);
    float* bvm1 = (float*)alloc((size_t)C1 * 4);
    float* bvm2 = (float*)alloc((size_t)C2 * 4);
    size_t fixed_end = off;
    float* acc2 = acc1;  // conv1 fp32 accum dead once h1b built

    // region: holds Q/K (conv QK phases) or Z (aggregation phases)
    size_t region = ws_size > fixed_end ? ws_size - fixed_end : 0;
    _Float16* Qbuf = (_Float16*)(base + fixed_end);
    _Float16* Kbuf = (_Float16*)(base + fixed_end + (((size_t)NN * C1 * 2 + 255) & ~(size_t)255));
    _Float16* Zbuf = Qbuf;
    // conv2 z-group size: largest Gz with NN*Gz*C1*2 <= region (>=2 fits the proven 75MB footprint)
    int Gz = 1;
    for (int cand = 8; cand >= 1; cand >>= 1)
        if ((size_t)NN * cand * C1 * 2 <= region) { Gz = cand; break; }

    const dim3 blk(256);
    const float sc1 = 1.0f / sqrtf((float)C1);
    const float sc2 = 1.0f / sqrtf((float)C2);
    const int edge_blocks = (NE * 64) / 256;
    const int node_blocks = (NN * 64) / 256;
    const int gy = (NN + 127) / 128;

    // ---- conversions ----
    cvt_f16<<<((size_t)NN * FIN + 255) / 256, blk, 0, stream>>>(x, xb, NN * FIN);
    {
        dim3 tb(32, 8);
        transpose_cvt<<<dim3(NHEAD * C1 / 32, FIN / 32), tb, 0, stream>>>(Wq1, wtq1, FIN, NHEAD * C1);
        transpose_cvt<<<dim3(NHEAD * C1 / 32, FIN / 32), tb, 0, stream>>>(Wk1, wtk1, FIN, NHEAD * C1);
        transpose_stack<<<dim3(C1 / 32, FIN / 32, NHEAD), tb, 0, stream>>>(Wv1, bvs1, FIN, C1);
        transpose_cvt<<<dim3(C1 / 32, FIN / 32),         tb, 0, stream>>>(Ws1, wts1, FIN, C1);
        transpose_cvt<<<dim3(NHEAD * C2 / 32, C1 / 32),  tb, 0, stream>>>(Wq2, wtq2, C1, NHEAD * C2);
        transpose_cvt<<<dim3(NHEAD * C2 / 32, C1 / 32),  tb, 0, stream>>>(Wk2, wtk2, C1, NHEAD * C2);
        transpose_stack<<<dim3(C2 / 32, C1 / 32, NHEAD), tb, 0, stream>>>(Wv2, bvs2, C1, C2);
        transpose_cvt<<<dim3(C2 / 32, C1 / 32),          tb, 0, stream>>>(Ws2, wts2, C1, C2);
    }
    bvmean_k<<<(C1 + 255) / 256, blk, 0, stream>>>(bv1, bvm1, C1);
    bvmean_k<<<(C2 + 255) / 256, blk, 0, stream>>>(bv2, bvm2, C2);

    // ---- CSR by dst ----
    zero_i32<<<(NN + 255) / 256, blk, 0, stream>>>(deg, NN);
    hist_dst<<<(NE + 255) / 256, blk, 0, stream>>>(dst, deg);
    scan_deg<<<1, blk, 0, stream>>>(deg, rowptr, cursor, NN);
    scatter_edges<<<(NE + 255) / 256, blk, 0, stream>>>(dst, cursor, eids);

    // ================ conv1 ================
    gemm_tn<false, false><<<dim3(C1 / 128, gy), blk, 0, stream>>>(
        xb, FIN, wts1, FIN, bs1, acc1, C1, NN, FIN);
    init_seg<<<(NN * NHEAD + 255) / 256, blk, 0, stream>>>(amaxU, denom, NN * NHEAD);
    for (int h = 0; h < NHEAD; ++h) {
        gemm_tn<true, false><<<dim3(C1 / 128, gy), blk, 0, stream>>>(
            xb, FIN, wtq1 + (size_t)h * C1 * FIN, FIN, bq1 + h * C1, Qbuf, C1, NN, FIN);
        gemm_tn<true, false><<<dim3(C1 / 128, gy), blk, 0, stream>>>(
            xb, FIN, wtk1 + (size_t)h * C1 * FIN, FIN, bk1 + h * C1, Kbuf, C1, NN, FIN);
        edge_alpha_f<C1><<<edge_blocks, blk, 0, stream>>>(Qbuf, Kbuf, src, dst, alpha, amaxU,
                                                          sc1, h);
    }
    edge_expsum<<<(NE * NHEAD + 255) / 256, blk, 0, stream>>>(alpha, dst, amaxU, ev, denom);
    // z-trick: Z1 [NN, 8*FIN] then acc1 += Z1 @ bvs1^T
    zaccum<FIN, NHEAD><<<node_blocks, blk, 0, stream>>>(xb, ev, denom, rowptr, eids, src,
                                                        Zbuf, 0);
    gemm_tn<false, true><<<dim3(C1 / 128, gy), blk, 0, stream>>>(
        Zbuf, NHEAD * FIN, bvs1, NHEAD * FIN, nullptr, acc1, C1, NN, NHEAD * FIN);
    elu_cvt_bias<<<((size_t)NN * C1 + 255) / 256, blk, 0, stream>>>(
        acc1, h1b, bvm1, deg, NN * C1, C1 - 1, 9);

    // ================ conv2 ================
    gemm_tn<false, false><<<dim3(C2 / 128, gy), blk, 0, stream>>>(
        h1b, C1, wts2, C1, bs2, acc2, C2, NN, C1);
    init_seg<<<(NN * NHEAD + 255) / 256, blk, 0, stream>>>(amaxU, denom, NN * NHEAD);
    for (int h = 0; h < NHEAD; ++h) {
        gemm_tn<true, false><<<dim3(C2 / 128, gy), blk, 0, stream>>>(
            h1b, C1, wtq2 + (size_t)h * C2 * C1, C1, bq2 + h * C2, Qbuf, C2, NN, C1);
        gemm_tn<true, false><<<dim3(C2 / 128, gy), blk, 0, stream>>>(
            h1b, C1, wtk2 + (size_t)h * C2 * C1, C1, bk2 + h * C2, Kbuf, C2, NN, C1);
        edge_alpha_f<C2><<<edge_blocks, blk, 0, stream>>>(Qbuf, Kbuf, src, dst, alpha, amaxU,
                                                          sc2, h);
    }
    edge_expsum<<<(NE * NHEAD + 255) / 256, blk, 0, stream>>>(alpha, dst, amaxU, ev, denom);
    for (int hb = 0; hb < NHEAD; hb += Gz) {
        switch (Gz) {
        case 8: zaccum<C1, 8><<<node_blocks, blk, 0, stream>>>(h1b, ev, denom, rowptr, eids, src, Zbuf, hb); break;
        case 4: zaccum<C1, 4><<<node_blocks, blk, 0, stream>>>(h1b, ev, denom, rowptr, eids, src, Zbuf, hb); break;
        case 2: zaccum<C1, 2><<<node_blocks, blk, 0, stream>>>(h1b, ev, denom, rowptr, eids, src, Zbuf, hb); break;
        default: zaccum<C1, 1><<<node_blocks, blk, 0, stream>>>(h1b, ev, denom, rowptr, eids, src, Zbuf, hb); break;
        }
        gemm_tn<false, true><<<dim3(C2 / 128, gy), blk, 0, stream>>>(
            Zbuf, Gz * C1, bvs2 + (size_t)hb * C1, NHEAD * C1, nullptr, acc2, C2, NN, Gz * C1);
    }
    elu_bias<<<((size_t)NN * C2 + 255) / 256, blk, 0, stream>>>(
        acc2, bvm2, deg, NN * C2, C2 - 1, 8);

    // ================ fused pooling + fc ================
    pool_fused<<<NB, blk, 0, stream>>>(acc2, Wg, bg, batch, Wf, bf, alpha, (float*)d_out);
}